// Round 6
// baseline (336.621 us; speedup 1.0000x reference)
//
#include <hip/hip_runtime.h>

#define N_NODES 50000
#define N_EDGES 800000
#define D_INF 64
#define D_HIDF 128

#define SCAN_CHUNK 1024
#define SCAN_NBLK ((N_NODES + SCAN_CHUNK - 1) / SCAN_CHUNK)  // 49

// ---------------------------------------------------------------------------
// CSR build: zero -> histogram -> 3-pass scan (also emits cursor) -> fill
// ---------------------------------------------------------------------------

__global__ void zero_kernel(int* __restrict__ p, int n) {
    int i = blockIdx.x * blockDim.x + threadIdx.x;
    if (i < n) p[i] = 0;
}

__global__ void hist_kernel(const int* __restrict__ dst, int* __restrict__ cnt) {
    int e = blockIdx.x * blockDim.x + threadIdx.x;
    if (e < N_EDGES) atomicAdd(&cnt[dst[e]], 1);
}

__global__ void __launch_bounds__(256) scan1_kernel(const int* __restrict__ cnt,
                                                    int* __restrict__ rowptr,
                                                    int* __restrict__ bsum) {
    __shared__ int wsum[4];
    int tid = threadIdx.x;
    int lane = tid & 63;
    int wv = tid >> 6;
    int base = blockIdx.x * SCAN_CHUNK + tid * 4;

    int v0 = 0, v1 = 0, v2 = 0, v3 = 0;
    if (base + 3 < N_NODES) {
        int4 q = *reinterpret_cast<const int4*>(cnt + base);
        v0 = q.x; v1 = q.y; v2 = q.z; v3 = q.w;
    } else {
        if (base + 0 < N_NODES) v0 = cnt[base + 0];
        if (base + 1 < N_NODES) v1 = cnt[base + 1];
        if (base + 2 < N_NODES) v2 = cnt[base + 2];
        if (base + 3 < N_NODES) v3 = cnt[base + 3];
    }
    int s = v0 + v1 + v2 + v3;
    int incl = s;
#pragma unroll
    for (int off = 1; off < 64; off <<= 1) {
        int t = __shfl_up(incl, off);
        if (lane >= off) incl += t;
    }
    if (lane == 63) wsum[wv] = incl;
    __syncthreads();
    if (tid == 0) {
        wsum[1] += wsum[0];
        wsum[2] += wsum[1];
        wsum[3] += wsum[2];
    }
    __syncthreads();
    int off0 = ((wv > 0) ? wsum[wv - 1] : 0) + (incl - s);
    int p0 = off0 + v0, p1 = p0 + v1, p2 = p1 + v2, p3 = p2 + v3;
    if (base + 0 < N_NODES) rowptr[base + 1] = p0;
    if (base + 1 < N_NODES) rowptr[base + 2] = p1;
    if (base + 2 < N_NODES) rowptr[base + 3] = p2;
    if (base + 3 < N_NODES) rowptr[base + 4] = p3;
    if (tid == 0) {
        bsum[blockIdx.x] = wsum[3];
        if (blockIdx.x == 0) rowptr[0] = 0;
    }
}

__global__ void scan2_kernel(int* __restrict__ bsum) {
    int lane = threadIdx.x;  // blockDim = 64
    int v = (lane < SCAN_NBLK) ? bsum[lane] : 0;
    int incl = v;
#pragma unroll
    for (int off = 1; off < 64; off <<= 1) {
        int t = __shfl_up(incl, off);
        if (lane >= off) incl += t;
    }
    if (lane < SCAN_NBLK) bsum[lane] = incl - v;
}

// Pass 3: add block offsets AND emit cursor = final rowptr value (so fill
// needs only one atomic, no separate rowptr read, no cursor zeroing).
__global__ void scan3_kernel(int* __restrict__ rowptr, const int* __restrict__ bsum,
                             int* __restrict__ cursor) {
    int add = bsum[blockIdx.x];
    int base = blockIdx.x * SCAN_CHUNK + threadIdx.x * 4;
#pragma unroll
    for (int i = 0; i < 4; i++) {
        if (base + i < N_NODES) {
            int v = rowptr[base + i + 1] + add;
            rowptr[base + i + 1] = v;
            if (base + i + 1 < N_NODES) cursor[base + i + 1] = v;
        }
    }
    if (blockIdx.x == 0 && threadIdx.x == 0) cursor[0] = 0;
}

__global__ void fill_kernel(const int* __restrict__ src, const int* __restrict__ dst,
                            int* __restrict__ cursor, int* __restrict__ elist) {
    int e = blockIdx.x * blockDim.x + threadIdx.x;
    if (e < N_EDGES) {
        int pos = atomicAdd(&cursor[dst[e]], 1);
        elist[pos] = src[e];
    }
}

// One wave per node: lane d accumulates feature d over the node's edge list.
// agg = x + sum_{neighbors} x[src]   (EPS = 0 folded)
__global__ void __launch_bounds__(256) gather_kernel(const float* __restrict__ x,
                                                     const int* __restrict__ rowptr,
                                                     const int* __restrict__ elist,
                                                     float* __restrict__ agg) {
    int wid = (blockIdx.x * blockDim.x + threadIdx.x) >> 6;
    int lane = threadIdx.x & 63;
    if (wid >= N_NODES) return;
    int beg = rowptr[wid];
    int end = rowptr[wid + 1];
    float s = x[(size_t)wid * D_INF + lane];
    float s2 = 0.f;
    int e = beg;
    for (; e + 7 < end; e += 8) {
        int i0 = elist[e + 0];
        int i1 = elist[e + 1];
        int i2 = elist[e + 2];
        int i3 = elist[e + 3];
        int i4 = elist[e + 4];
        int i5 = elist[e + 5];
        int i6 = elist[e + 6];
        int i7 = elist[e + 7];
        float v0 = x[(size_t)i0 * D_INF + lane];
        float v1 = x[(size_t)i1 * D_INF + lane];
        float v2 = x[(size_t)i2 * D_INF + lane];
        float v3 = x[(size_t)i3 * D_INF + lane];
        float v4 = x[(size_t)i4 * D_INF + lane];
        float v5 = x[(size_t)i5 * D_INF + lane];
        float v6 = x[(size_t)i6 * D_INF + lane];
        float v7 = x[(size_t)i7 * D_INF + lane];
        s += (v0 + v1) + (v2 + v3);
        s2 += (v4 + v5) + (v6 + v7);
    }
    for (; e < end; e++) {
        s += x[(size_t)elist[e] * D_INF + lane];
    }
    agg[(size_t)wid * D_INF + lane] = s + s2;
}

// ---------------------------------------------------------------------------
// W1 transpose: W1T[j*64 + l] = W1[l*128 + j] (so W1T row j is contiguous)
// ---------------------------------------------------------------------------

__global__ void transpose_w1_kernel(const float* __restrict__ W1, float* __restrict__ W1T) {
    int i = blockIdx.x * blockDim.x + threadIdx.x;
    if (i < D_INF * D_HIDF) {
        int l = i / D_HIDF;
        int j = i % D_HIDF;
        W1T[j * D_INF + l] = W1[i];
    }
}

// ---------------------------------------------------------------------------
// MLP v4: 64-node tile, 512 threads = 8 waves. Wave w owns hidden slice
// j in [16w, 16w+16). Weight rows are wave-uniform -> scalar (SMEM) loads;
// inner loops are pure v_fmac v,s,v. Lane's agg row lives in 64 VGPRs.
// Partial outputs reduced across waves via LDS fp32 atomics.
// ---------------------------------------------------------------------------

#define MLP_TILE 64
#define ROW_LD 68   // padded LDS row stride; gcd(17,32)=1 -> conflict-free

__global__ void __launch_bounds__(512) mlp_kernel(const float* __restrict__ agg,
                                                  const float* __restrict__ w1t,
                                                  const float* __restrict__ b1,
                                                  const float* __restrict__ W2,
                                                  const float* __restrict__ b2,
                                                  float* __restrict__ out) {
    __shared__ float atile[MLP_TILE * ROW_LD];  // 17.4 KB
    __shared__ float otile[MLP_TILE * ROW_LD];  // 17.4 KB
    int tid = threadIdx.x;
    int lane = tid & 63;
    int wq = __builtin_amdgcn_readfirstlane(tid >> 6);  // 0..7, provably uniform
    int nb = blockIdx.x * MLP_TILE;

    // stage agg tile: 4096 floats; 512 threads x 8 floats, coalesced
    {
        int r = tid >> 3;
        int c = (tid & 7) * 8;
        int node = nb + r;
        float4 v0 = make_float4(0.f, 0.f, 0.f, 0.f), v1 = v0;
        if (node < N_NODES) {
            v0 = *reinterpret_cast<const float4*>(agg + (size_t)node * D_INF + c);
            v1 = *reinterpret_cast<const float4*>(agg + (size_t)node * D_INF + c + 4);
        }
        *reinterpret_cast<float4*>(&atile[r * ROW_LD + c]) = v0;
        *reinterpret_cast<float4*>(&atile[r * ROW_LD + c + 4]) = v1;
    }
    // zero output tile
    for (int i = tid * 4; i < MLP_TILE * ROW_LD; i += 512 * 4) {
        *reinterpret_cast<float4*>(&otile[i]) = make_float4(0.f, 0.f, 0.f, 0.f);
    }
    __syncthreads();

    // lane's agg row -> 64 VGPRs (16 conflict-free ds_read_b128)
    float arow[64];
#pragma unroll
    for (int i = 0; i < 16; i++) {
        float4 v = *reinterpret_cast<const float4*>(&atile[lane * ROW_LD + i * 4]);
        arow[i * 4 + 0] = v.x;
        arow[i * 4 + 1] = v.y;
        arow[i * 4 + 2] = v.z;
        arow[i * 4 + 3] = v.w;
    }

    // phase 1: h[jj] for j = wq*16 + jj; W1T row via scalar loads
    float h[16];
    const float* w1base = w1t + wq * 16 * D_INF;
    const float* b1base = b1 + wq * 16;
#pragma unroll
    for (int jj = 0; jj < 16; jj++) {
        const float* row = w1base + jj * D_INF;
        float p0 = 0.f, p1 = 0.f, p2 = 0.f, p3 = 0.f;
#pragma unroll
        for (int l = 0; l < 64; l += 4) {
            p0 += row[l + 0] * arow[l + 0];
            p1 += row[l + 1] * arow[l + 1];
            p2 += row[l + 2] * arow[l + 2];
            p3 += row[l + 3] * arow[l + 3];
        }
        h[jj] = fmaxf(b1base[jj] + ((p0 + p1) + (p2 + p3)), 0.f);
    }

    // phase 2: partial out over this wave's 16 j's; W2 row via scalar loads
    float acc[64];
#pragma unroll
    for (int d = 0; d < 64; d++) acc[d] = 0.f;
    const float* w2base = W2 + wq * 16 * D_INF;
#pragma unroll
    for (int jj = 0; jj < 16; jj++) {
        const float* row = w2base + jj * D_INF;
        float hv = h[jj];
#pragma unroll
        for (int d = 0; d < 64; d++) {
            acc[d] += hv * row[d];
        }
    }

    // cross-wave reduction via LDS fp32 atomics (conflict-free addressing)
#pragma unroll
    for (int d = 0; d < 64; d++) {
        atomicAdd(&otile[lane * ROW_LD + d], acc[d]);
    }
    __syncthreads();

    // write out tile + b2
    {
        int r = tid >> 3;
        int c = (tid & 7) * 8;
        int node = nb + r;
        if (node < N_NODES) {
            float4 v0 = *reinterpret_cast<float4*>(&otile[r * ROW_LD + c]);
            float4 v1 = *reinterpret_cast<float4*>(&otile[r * ROW_LD + c + 4]);
            float4 bb0 = *reinterpret_cast<const float4*>(b2 + c);
            float4 bb1 = *reinterpret_cast<const float4*>(b2 + c + 4);
            v0.x += bb0.x; v0.y += bb0.y; v0.z += bb0.z; v0.w += bb0.w;
            v1.x += bb1.x; v1.y += bb1.y; v1.z += bb1.z; v1.w += bb1.w;
            *reinterpret_cast<float4*>(out + (size_t)node * D_INF + c) = v0;
            *reinterpret_cast<float4*>(out + (size_t)node * D_INF + c + 4) = v1;
        }
    }
}

// ---------------------------------------------------------------------------
// Fallback (atomic scatter) — used only if ws_size is too small
// ---------------------------------------------------------------------------

__global__ void init_agg_kernel(const float* __restrict__ x, float* __restrict__ agg) {
    int i = blockIdx.x * blockDim.x + threadIdx.x;
    int n4 = N_NODES * D_INF / 4;
    if (i < n4) {
        reinterpret_cast<float4*>(agg)[i] = reinterpret_cast<const float4*>(x)[i];
    }
}

__global__ void scatter_kernel(const float* __restrict__ x,
                               const int* __restrict__ src,
                               const int* __restrict__ dst,
                               float* __restrict__ agg) {
    int tid = blockIdx.x * blockDim.x + threadIdx.x;
    int e = tid >> 6;
    int d = tid & 63;
    if (e < N_EDGES) {
        atomicAdd(&agg[(size_t)dst[e] * D_INF + d], x[(size_t)src[e] * D_INF + d]);
    }
}

// ---------------------------------------------------------------------------

extern "C" void kernel_launch(void* const* d_in, const int* in_sizes, int n_in,
                              void* d_out, int out_size, void* d_ws, size_t ws_size,
                              hipStream_t stream) {
    const float* x   = (const float*)d_in[0];
    const int* edge  = (const int*)d_in[1];   // [2, E]: src = edge, dst = edge + E
    const float* W1  = (const float*)d_in[2];
    const float* b1  = (const float*)d_in[3];
    const float* W2  = (const float*)d_in[4];
    const float* b2  = (const float*)d_in[5];
    float* out       = (float*)d_out;

    const int* src = edge;
    const int* dst = edge + N_EDGES;

    // Workspace layout:
    //   agg   : N*64 floats (12.8 MB)
    //   W1T   : 128*64 floats (32 KB)
    //   cnt   : N ints
    //   cursor: N ints
    //   rowptr: N+1 ints
    //   bsum  : 64 ints
    //   elist : E ints (3.2 MB)
    float* agg  = (float*)d_ws;
    float* W1T  = agg + (size_t)N_NODES * D_INF;
    int* cnt    = (int*)(W1T + D_INF * D_HIDF);
    int* cursor = cnt + N_NODES;
    int* rowptr = cursor + N_NODES;
    int* bsum   = rowptr + N_NODES + 1;
    int* elist  = bsum + 64;

    size_t needed = ((size_t)N_NODES * D_INF + D_INF * D_HIDF) * 4
                  + ((size_t)3 * N_NODES + 1 + 64 + N_EDGES) * 4;

    transpose_w1_kernel<<<(D_INF * D_HIDF + 255) / 256, 256, 0, stream>>>(W1, W1T);

    if (ws_size >= needed) {
        zero_kernel<<<(N_NODES + 255) / 256, 256, 0, stream>>>(cnt, N_NODES);
        hist_kernel<<<(N_EDGES + 255) / 256, 256, 0, stream>>>(dst, cnt);
        scan1_kernel<<<SCAN_NBLK, 256, 0, stream>>>(cnt, rowptr, bsum);
        scan2_kernel<<<1, 64, 0, stream>>>(bsum);
        scan3_kernel<<<SCAN_NBLK, 256, 0, stream>>>(rowptr, bsum, cursor);
        fill_kernel<<<(N_EDGES + 255) / 256, 256, 0, stream>>>(src, dst, cursor, elist);
        int threads = N_NODES * 64;
        gather_kernel<<<(threads + 255) / 256, 256, 0, stream>>>(x, rowptr, elist, agg);
    } else {
        int n4 = N_NODES * D_INF / 4;
        init_agg_kernel<<<(n4 + 255) / 256, 256, 0, stream>>>(x, agg);
        int work = N_EDGES * D_INF;
        scatter_kernel<<<(work + 255) / 256, 256, 0, stream>>>(x, src, dst, agg);
    }

    // MLP: 64-node tiles, 8 waves/block
    mlp_kernel<<<(N_NODES + MLP_TILE - 1) / MLP_TILE, 512, 0, stream>>>(
        agg, W1T, b1, W2, b2, out);
}

// Round 7
// 215.167 us; speedup vs baseline: 1.5645x; 1.5645x over previous
//
#include <hip/hip_runtime.h>

#define N_NODES 50000
#define N_EDGES 800000
#define D_INF 64
#define D_HIDF 128

#define SCAN_CHUNK 1024
#define SCAN_NBLK ((N_NODES + SCAN_CHUNK - 1) / SCAN_CHUNK)  // 49

// ---------------------------------------------------------------------------
// CSR build: zero -> histogram -> 3-pass scan (also emits cursor) -> fill
// ---------------------------------------------------------------------------

__global__ void zero_kernel(int* __restrict__ p, int n) {
    int i = blockIdx.x * blockDim.x + threadIdx.x;
    if (i < n) p[i] = 0;
}

__global__ void hist_kernel(const int* __restrict__ dst, int* __restrict__ cnt) {
    int e = blockIdx.x * blockDim.x + threadIdx.x;
    if (e < N_EDGES) atomicAdd(&cnt[dst[e]], 1);
}

__global__ void __launch_bounds__(256) scan1_kernel(const int* __restrict__ cnt,
                                                    int* __restrict__ rowptr,
                                                    int* __restrict__ bsum) {
    __shared__ int wsum[4];
    int tid = threadIdx.x;
    int lane = tid & 63;
    int wv = tid >> 6;
    int base = blockIdx.x * SCAN_CHUNK + tid * 4;

    int v0 = 0, v1 = 0, v2 = 0, v3 = 0;
    if (base + 3 < N_NODES) {
        int4 q = *reinterpret_cast<const int4*>(cnt + base);
        v0 = q.x; v1 = q.y; v2 = q.z; v3 = q.w;
    } else {
        if (base + 0 < N_NODES) v0 = cnt[base + 0];
        if (base + 1 < N_NODES) v1 = cnt[base + 1];
        if (base + 2 < N_NODES) v2 = cnt[base + 2];
        if (base + 3 < N_NODES) v3 = cnt[base + 3];
    }
    int s = v0 + v1 + v2 + v3;
    int incl = s;
#pragma unroll
    for (int off = 1; off < 64; off <<= 1) {
        int t = __shfl_up(incl, off);
        if (lane >= off) incl += t;
    }
    if (lane == 63) wsum[wv] = incl;
    __syncthreads();
    if (tid == 0) {
        wsum[1] += wsum[0];
        wsum[2] += wsum[1];
        wsum[3] += wsum[2];
    }
    __syncthreads();
    int off0 = ((wv > 0) ? wsum[wv - 1] : 0) + (incl - s);
    int p0 = off0 + v0, p1 = p0 + v1, p2 = p1 + v2, p3 = p2 + v3;
    if (base + 0 < N_NODES) rowptr[base + 1] = p0;
    if (base + 1 < N_NODES) rowptr[base + 2] = p1;
    if (base + 2 < N_NODES) rowptr[base + 3] = p2;
    if (base + 3 < N_NODES) rowptr[base + 4] = p3;
    if (tid == 0) {
        bsum[blockIdx.x] = wsum[3];
        if (blockIdx.x == 0) rowptr[0] = 0;
    }
}

__global__ void scan2_kernel(int* __restrict__ bsum) {
    int lane = threadIdx.x;  // blockDim = 64
    int v = (lane < SCAN_NBLK) ? bsum[lane] : 0;
    int incl = v;
#pragma unroll
    for (int off = 1; off < 64; off <<= 1) {
        int t = __shfl_up(incl, off);
        if (lane >= off) incl += t;
    }
    if (lane < SCAN_NBLK) bsum[lane] = incl - v;
}

// Pass 3: add block offsets AND emit cursor = final rowptr value.
__global__ void scan3_kernel(int* __restrict__ rowptr, const int* __restrict__ bsum,
                             int* __restrict__ cursor) {
    int add = bsum[blockIdx.x];
    int base = blockIdx.x * SCAN_CHUNK + threadIdx.x * 4;
#pragma unroll
    for (int i = 0; i < 4; i++) {
        if (base + i < N_NODES) {
            int v = rowptr[base + i + 1] + add;
            rowptr[base + i + 1] = v;
            if (base + i + 1 < N_NODES) cursor[base + i + 1] = v;
        }
    }
    if (blockIdx.x == 0 && threadIdx.x == 0) cursor[0] = 0;
}

__global__ void fill_kernel(const int* __restrict__ src, const int* __restrict__ dst,
                            int* __restrict__ cursor, int* __restrict__ elist) {
    int e = blockIdx.x * blockDim.x + threadIdx.x;
    if (e < N_EDGES) {
        int pos = atomicAdd(&cursor[dst[e]], 1);
        elist[pos] = src[e];
    }
}

// One wave per node: lane d accumulates feature d over the node's edge list.
// agg = x + sum_{neighbors} x[src]   (EPS = 0 folded)
__global__ void __launch_bounds__(256) gather_kernel(const float* __restrict__ x,
                                                     const int* __restrict__ rowptr,
                                                     const int* __restrict__ elist,
                                                     float* __restrict__ agg) {
    int wid = (blockIdx.x * blockDim.x + threadIdx.x) >> 6;
    int lane = threadIdx.x & 63;
    if (wid >= N_NODES) return;
    int beg = rowptr[wid];
    int end = rowptr[wid + 1];
    float s = x[(size_t)wid * D_INF + lane];
    float s2 = 0.f;
    int e = beg;
    for (; e + 7 < end; e += 8) {
        int i0 = elist[e + 0];
        int i1 = elist[e + 1];
        int i2 = elist[e + 2];
        int i3 = elist[e + 3];
        int i4 = elist[e + 4];
        int i5 = elist[e + 5];
        int i6 = elist[e + 6];
        int i7 = elist[e + 7];
        float v0 = x[(size_t)i0 * D_INF + lane];
        float v1 = x[(size_t)i1 * D_INF + lane];
        float v2 = x[(size_t)i2 * D_INF + lane];
        float v3 = x[(size_t)i3 * D_INF + lane];
        float v4 = x[(size_t)i4 * D_INF + lane];
        float v5 = x[(size_t)i5 * D_INF + lane];
        float v6 = x[(size_t)i6 * D_INF + lane];
        float v7 = x[(size_t)i7 * D_INF + lane];
        s += (v0 + v1) + (v2 + v3);
        s2 += (v4 + v5) + (v6 + v7);
    }
    for (; e < end; e++) {
        s += x[(size_t)elist[e] * D_INF + lane];
    }
    agg[(size_t)wid * D_INF + lane] = s + s2;
}

// ---------------------------------------------------------------------------
// W1 transpose: W1T[j*64 + l] = W1[l*128 + j]
// ---------------------------------------------------------------------------

__global__ void transpose_w1_kernel(const float* __restrict__ W1, float* __restrict__ W1T) {
    int i = blockIdx.x * blockDim.x + threadIdx.x;
    if (i < D_INF * D_HIDF) {
        int l = i / D_HIDF;
        int j = i % D_HIDF;
        W1T[j * D_INF + l] = W1[i];
    }
}

// ---------------------------------------------------------------------------
// MLP v5: 64-node tile, 512 threads = 8 waves. lane = node.
// Phase 1: wave w owns j-slice [16w,16w+16); only h[16] live per thread;
//          agg from LDS 4 floats at a time; W1T rows via wave-uniform s_load.
// h exchanged via LDS htile. Phase 2: wave w owns d-slice [8w,8w+8);
//          only acc[8] live; W2 via s_load; direct global store.
// ---------------------------------------------------------------------------

#define MLP_TILE 64
#define ROW_LD 68    // atile dword stride
#define H_LD 132     // htile dword stride (multiple of 4 for b128)

__global__ void __launch_bounds__(512) mlp_kernel(const float* __restrict__ agg,
                                                  const float* __restrict__ w1t,
                                                  const float* __restrict__ b1,
                                                  const float* __restrict__ W2,
                                                  const float* __restrict__ b2,
                                                  float* __restrict__ out) {
    __shared__ float atile[MLP_TILE * ROW_LD];  // 17.4 KB
    __shared__ float htile[MLP_TILE * H_LD];    // 33.8 KB
    int tid = threadIdx.x;
    int lane = tid & 63;
    int wqu = __builtin_amdgcn_readfirstlane(tid >> 6);  // 0..7, uniform SGPR
    int nb = blockIdx.x * MLP_TILE;

    // stage agg tile: 4096 floats; 512 threads x 8 floats, coalesced
    {
        int r = tid >> 3;
        int c = (tid & 7) * 8;
        int node = nb + r;
        float4 v0 = make_float4(0.f, 0.f, 0.f, 0.f), v1 = v0;
        if (node < N_NODES) {
            v0 = *reinterpret_cast<const float4*>(agg + (size_t)node * D_INF + c);
            v1 = *reinterpret_cast<const float4*>(agg + (size_t)node * D_INF + c + 4);
        }
        *reinterpret_cast<float4*>(&atile[r * ROW_LD + c]) = v0;
        *reinterpret_cast<float4*>(&atile[r * ROW_LD + c + 4]) = v1;
    }
    __syncthreads();

    // ---- phase 1: h[jj] for j = wqu*16 + jj, node = lane ----
    {
        const float* w1r = w1t + wqu * 16 * D_INF;  // uniform base
        const float* b1r = b1 + wqu * 16;
        float h[16];
#pragma unroll
        for (int jj = 0; jj < 16; jj++) h[jj] = b1r[jj];

#pragma unroll 4
        for (int l4 = 0; l4 < 16; l4++) {
            float4 a = *reinterpret_cast<const float4*>(&atile[lane * ROW_LD + l4 * 4]);
#pragma unroll
            for (int jj = 0; jj < 16; jj++) {
                h[jj] += a.x * w1r[jj * D_INF + l4 * 4 + 0]
                       + a.y * w1r[jj * D_INF + l4 * 4 + 1]
                       + a.z * w1r[jj * D_INF + l4 * 4 + 2]
                       + a.w * w1r[jj * D_INF + l4 * 4 + 3];
            }
        }
        // ReLU + write to htile[lane][wqu*16 + jj]
#pragma unroll
        for (int q = 0; q < 4; q++) {
            float4 v = make_float4(fmaxf(h[q * 4 + 0], 0.f), fmaxf(h[q * 4 + 1], 0.f),
                                   fmaxf(h[q * 4 + 2], 0.f), fmaxf(h[q * 4 + 3], 0.f));
            *reinterpret_cast<float4*>(&htile[lane * H_LD + wqu * 16 + q * 4]) = v;
        }
    }
    __syncthreads();

    // ---- phase 2: out[node][wqu*8 + k], node = lane ----
    {
        const float* w2r = W2 + wqu * 8;  // uniform column-slice base
        const float* b2r = b2 + wqu * 8;
        float acc[8];
#pragma unroll
        for (int k = 0; k < 8; k++) acc[k] = b2r[k];

#pragma unroll 4
        for (int j4 = 0; j4 < 32; j4++) {
            float4 hv = *reinterpret_cast<const float4*>(&htile[lane * H_LD + j4 * 4]);
#pragma unroll
            for (int k = 0; k < 8; k++) {
                acc[k] += hv.x * w2r[(j4 * 4 + 0) * D_INF + k]
                        + hv.y * w2r[(j4 * 4 + 1) * D_INF + k]
                        + hv.z * w2r[(j4 * 4 + 2) * D_INF + k]
                        + hv.w * w2r[(j4 * 4 + 3) * D_INF + k];
            }
        }

        int node = nb + lane;
        if (node < N_NODES) {
            *reinterpret_cast<float4*>(out + (size_t)node * D_INF + wqu * 8) =
                make_float4(acc[0], acc[1], acc[2], acc[3]);
            *reinterpret_cast<float4*>(out + (size_t)node * D_INF + wqu * 8 + 4) =
                make_float4(acc[4], acc[5], acc[6], acc[7]);
        }
    }
}

// ---------------------------------------------------------------------------
// Fallback (atomic scatter) — used only if ws_size is too small
// ---------------------------------------------------------------------------

__global__ void init_agg_kernel(const float* __restrict__ x, float* __restrict__ agg) {
    int i = blockIdx.x * blockDim.x + threadIdx.x;
    int n4 = N_NODES * D_INF / 4;
    if (i < n4) {
        reinterpret_cast<float4*>(agg)[i] = reinterpret_cast<const float4*>(x)[i];
    }
}

__global__ void scatter_kernel(const float* __restrict__ x,
                               const int* __restrict__ src,
                               const int* __restrict__ dst,
                               float* __restrict__ agg) {
    int tid = blockIdx.x * blockDim.x + threadIdx.x;
    int e = tid >> 6;
    int d = tid & 63;
    if (e < N_EDGES) {
        atomicAdd(&agg[(size_t)dst[e] * D_INF + d], x[(size_t)src[e] * D_INF + d]);
    }
}

// ---------------------------------------------------------------------------

extern "C" void kernel_launch(void* const* d_in, const int* in_sizes, int n_in,
                              void* d_out, int out_size, void* d_ws, size_t ws_size,
                              hipStream_t stream) {
    const float* x   = (const float*)d_in[0];
    const int* edge  = (const int*)d_in[1];   // [2, E]: src = edge, dst = edge + E
    const float* W1  = (const float*)d_in[2];
    const float* b1  = (const float*)d_in[3];
    const float* W2  = (const float*)d_in[4];
    const float* b2  = (const float*)d_in[5];
    float* out       = (float*)d_out;

    const int* src = edge;
    const int* dst = edge + N_EDGES;

    float* agg  = (float*)d_ws;
    float* W1T  = agg + (size_t)N_NODES * D_INF;
    int* cnt    = (int*)(W1T + D_INF * D_HIDF);
    int* cursor = cnt + N_NODES;
    int* rowptr = cursor + N_NODES;
    int* bsum   = rowptr + N_NODES + 1;
    int* elist  = bsum + 64;

    size_t needed = ((size_t)N_NODES * D_INF + D_INF * D_HIDF) * 4
                  + ((size_t)3 * N_NODES + 1 + 64 + N_EDGES) * 4;

    transpose_w1_kernel<<<(D_INF * D_HIDF + 255) / 256, 256, 0, stream>>>(W1, W1T);

    if (ws_size >= needed) {
        zero_kernel<<<(N_NODES + 255) / 256, 256, 0, stream>>>(cnt, N_NODES);
        hist_kernel<<<(N_EDGES + 255) / 256, 256, 0, stream>>>(dst, cnt);
        scan1_kernel<<<SCAN_NBLK, 256, 0, stream>>>(cnt, rowptr, bsum);
        scan2_kernel<<<1, 64, 0, stream>>>(bsum);
        scan3_kernel<<<SCAN_NBLK, 256, 0, stream>>>(rowptr, bsum, cursor);
        fill_kernel<<<(N_EDGES + 255) / 256, 256, 0, stream>>>(src, dst, cursor, elist);
        int threads = N_NODES * 64;
        gather_kernel<<<(threads + 255) / 256, 256, 0, stream>>>(x, rowptr, elist, agg);
    } else {
        int n4 = N_NODES * D_INF / 4;
        init_agg_kernel<<<(n4 + 255) / 256, 256, 0, stream>>>(x, agg);
        int work = N_EDGES * D_INF;
        scatter_kernel<<<(work + 255) / 256, 256, 0, stream>>>(x, src, dst, agg);
    }

    // MLP: 64-node tiles, 8 waves/block, scalar-pipe weights
    mlp_kernel<<<(N_NODES + MLP_TILE - 1) / MLP_TILE, 512, 0, stream>>>(
        agg, W1T, b1, W2, b2, out);
}

// Round 8
// 145.417 us; speedup vs baseline: 2.3149x; 1.4797x over previous
//
#include <hip/hip_runtime.h>

#define N_NODES 50000
#define N_EDGES 800000
#define D_INF 64
#define D_HIDF 128

#define SCAN_CHUNK 1024
#define SCAN_NBLK ((N_NODES + SCAN_CHUNK - 1) / SCAN_CHUNK)  // 49

typedef __attribute__((ext_vector_type(8))) short bf16x8v;  // 8 bf16 = 4 VGPRs
typedef __attribute__((ext_vector_type(4))) float f32x4;

__device__ __forceinline__ ushort f2bf(float f) {
    unsigned int u = __builtin_bit_cast(unsigned int, f);
    u += 0x7FFF + ((u >> 16) & 1);  // RNE
    return (ushort)(u >> 16);
}

// ---------------------------------------------------------------------------
// CSR build: zero -> histogram -> 3-pass scan (also emits cursor) -> fill
// ---------------------------------------------------------------------------

__global__ void zero_kernel(int* __restrict__ p, int n) {
    int i = blockIdx.x * blockDim.x + threadIdx.x;
    if (i < n) p[i] = 0;
}

__global__ void hist_kernel(const int* __restrict__ dst, int* __restrict__ cnt) {
    int e = blockIdx.x * blockDim.x + threadIdx.x;
    if (e < N_EDGES) atomicAdd(&cnt[dst[e]], 1);
}

__global__ void __launch_bounds__(256) scan1_kernel(const int* __restrict__ cnt,
                                                    int* __restrict__ rowptr,
                                                    int* __restrict__ bsum) {
    __shared__ int wsum[4];
    int tid = threadIdx.x;
    int lane = tid & 63;
    int wv = tid >> 6;
    int base = blockIdx.x * SCAN_CHUNK + tid * 4;

    int v0 = 0, v1 = 0, v2 = 0, v3 = 0;
    if (base + 3 < N_NODES) {
        int4 q = *reinterpret_cast<const int4*>(cnt + base);
        v0 = q.x; v1 = q.y; v2 = q.z; v3 = q.w;
    } else {
        if (base + 0 < N_NODES) v0 = cnt[base + 0];
        if (base + 1 < N_NODES) v1 = cnt[base + 1];
        if (base + 2 < N_NODES) v2 = cnt[base + 2];
        if (base + 3 < N_NODES) v3 = cnt[base + 3];
    }
    int s = v0 + v1 + v2 + v3;
    int incl = s;
#pragma unroll
    for (int off = 1; off < 64; off <<= 1) {
        int t = __shfl_up(incl, off);
        if (lane >= off) incl += t;
    }
    if (lane == 63) wsum[wv] = incl;
    __syncthreads();
    if (tid == 0) {
        wsum[1] += wsum[0];
        wsum[2] += wsum[1];
        wsum[3] += wsum[2];
    }
    __syncthreads();
    int off0 = ((wv > 0) ? wsum[wv - 1] : 0) + (incl - s);
    int p0 = off0 + v0, p1 = p0 + v1, p2 = p1 + v2, p3 = p2 + v3;
    if (base + 0 < N_NODES) rowptr[base + 1] = p0;
    if (base + 1 < N_NODES) rowptr[base + 2] = p1;
    if (base + 2 < N_NODES) rowptr[base + 3] = p2;
    if (base + 3 < N_NODES) rowptr[base + 4] = p3;
    if (tid == 0) {
        bsum[blockIdx.x] = wsum[3];
        if (blockIdx.x == 0) rowptr[0] = 0;
    }
}

__global__ void scan2_kernel(int* __restrict__ bsum) {
    int lane = threadIdx.x;  // blockDim = 64
    int v = (lane < SCAN_NBLK) ? bsum[lane] : 0;
    int incl = v;
#pragma unroll
    for (int off = 1; off < 64; off <<= 1) {
        int t = __shfl_up(incl, off);
        if (lane >= off) incl += t;
    }
    if (lane < SCAN_NBLK) bsum[lane] = incl - v;
}

__global__ void scan3_kernel(int* __restrict__ rowptr, const int* __restrict__ bsum,
                             int* __restrict__ cursor) {
    int add = bsum[blockIdx.x];
    int base = blockIdx.x * SCAN_CHUNK + threadIdx.x * 4;
#pragma unroll
    for (int i = 0; i < 4; i++) {
        if (base + i < N_NODES) {
            int v = rowptr[base + i + 1] + add;
            rowptr[base + i + 1] = v;
            if (base + i + 1 < N_NODES) cursor[base + i + 1] = v;
        }
    }
    if (blockIdx.x == 0 && threadIdx.x == 0) cursor[0] = 0;
}

__global__ void fill_kernel(const int* __restrict__ src, const int* __restrict__ dst,
                            int* __restrict__ cursor, int* __restrict__ elist) {
    int e = blockIdx.x * blockDim.x + threadIdx.x;
    if (e < N_EDGES) {
        int pos = atomicAdd(&cursor[dst[e]], 1);
        elist[pos] = src[e];
    }
}

// One wave per node; lane d accumulates feature d. Writes agg in BF16.
// agg = x + sum_{neighbors} x[src]   (EPS = 0 folded)
__global__ void __launch_bounds__(256) gather_kernel(const float* __restrict__ x,
                                                     const int* __restrict__ rowptr,
                                                     const int* __restrict__ elist,
                                                     ushort* __restrict__ aggb) {
    int wid = (blockIdx.x * blockDim.x + threadIdx.x) >> 6;
    int lane = threadIdx.x & 63;
    if (wid >= N_NODES) return;
    int beg = rowptr[wid];
    int end = rowptr[wid + 1];
    float s = x[(size_t)wid * D_INF + lane];
    float s2 = 0.f;
    int e = beg;
    for (; e + 7 < end; e += 8) {
        int i0 = elist[e + 0];
        int i1 = elist[e + 1];
        int i2 = elist[e + 2];
        int i3 = elist[e + 3];
        int i4 = elist[e + 4];
        int i5 = elist[e + 5];
        int i6 = elist[e + 6];
        int i7 = elist[e + 7];
        float v0 = x[(size_t)i0 * D_INF + lane];
        float v1 = x[(size_t)i1 * D_INF + lane];
        float v2 = x[(size_t)i2 * D_INF + lane];
        float v3 = x[(size_t)i3 * D_INF + lane];
        float v4 = x[(size_t)i4 * D_INF + lane];
        float v5 = x[(size_t)i5 * D_INF + lane];
        float v6 = x[(size_t)i6 * D_INF + lane];
        float v7 = x[(size_t)i7 * D_INF + lane];
        s += (v0 + v1) + (v2 + v3);
        s2 += (v4 + v5) + (v6 + v7);
    }
    for (; e < end; e++) {
        s += x[(size_t)elist[e] * D_INF + lane];
    }
    aggb[(size_t)wid * D_INF + lane] = f2bf(s + s2);
}

// ---------------------------------------------------------------------------
// Weight prep: bf16 transposed copies. w1tb[j][l] = W1[l][j]; w2tb[d][j] = W2[j][d]
// ---------------------------------------------------------------------------

__global__ void prep_weights_kernel(const float* __restrict__ W1,
                                    const float* __restrict__ W2,
                                    ushort* __restrict__ w1tb,
                                    ushort* __restrict__ w2tb) {
    int i = blockIdx.x * blockDim.x + threadIdx.x;
    if (i < D_INF * D_HIDF) {
        int j = i >> 6, l = i & 63;
        w1tb[i] = f2bf(W1[l * D_HIDF + j]);
        int d = i >> 7, jj = i & 127;
        w2tb[i] = f2bf(W2[jj * D_INF + d]);
    }
}

// ---------------------------------------------------------------------------
// MLP v6 (MFMA): 64-node tile, 256 threads = 4 waves. Wave w owns node rows
// [16w,16w+16) for BOTH GEMMs -> H is wave-private, no inter-GEMM barrier.
// GEMM1: H[64x128] = A[64x64] @ W1; GEMM2: OUT[64x64] = relu(H) @ W2.
// 16x16x32 bf16 MFMA; fragments are contiguous b128 LDS reads.
// ---------------------------------------------------------------------------

#define AT_LD 72     // atile row stride (u16); 72*2B=144B, 16B-aligned, 2-way banks
#define W1_LD 72
#define HT_LD 136    // 272B rows
#define W2_LD 136

__global__ void __launch_bounds__(256) mlp_mfma_kernel(
    const ushort* __restrict__ aggb, const ushort* __restrict__ w1tb,
    const float* __restrict__ b1v, const ushort* __restrict__ w2tb,
    const float* __restrict__ b2v, float* __restrict__ out)
{
    __shared__ __align__(16) ushort atile[64 * AT_LD];   //  9.2 KB
    __shared__ __align__(16) ushort w1s[128 * W1_LD];    // 18.4 KB
    __shared__ __align__(16) ushort w2s[64 * W2_LD];     // 17.4 KB
    __shared__ __align__(16) ushort htile[64 * HT_LD];   // 17.4 KB

    int tid = threadIdx.x;
    int lane = tid & 63;
    int wv = tid >> 6;
    int nb = blockIdx.x * 64;

    // stage atile (bf16 agg, zero-fill OOB rows): 512 chunks of 8 bf16
#pragma unroll
    for (int c = 0; c < 2; c++) {
        int chunk = tid + c * 256;
        int row = chunk >> 3;
        int col = (chunk & 7) * 8;
        ulonglong2 v;
        v.x = 0; v.y = 0;
        if (nb + row < N_NODES)
            v = *reinterpret_cast<const ulonglong2*>(aggb + (size_t)(nb + row) * D_INF + col);
        *reinterpret_cast<ulonglong2*>(&atile[row * AT_LD + col]) = v;
    }
    // stage w1s: 1024 chunks (rows of 64)
#pragma unroll
    for (int c = 0; c < 4; c++) {
        int chunk = tid + c * 256;
        int row = chunk >> 3;
        int col = (chunk & 7) * 8;
        *reinterpret_cast<ulonglong2*>(&w1s[row * W1_LD + col]) =
            *reinterpret_cast<const ulonglong2*>(w1tb + row * 64 + col);
    }
    // stage w2s: 1024 chunks (rows of 128)
#pragma unroll
    for (int c = 0; c < 4; c++) {
        int chunk = tid + c * 256;
        int row = chunk >> 4;
        int col = (chunk & 15) * 8;
        *reinterpret_cast<ulonglong2*>(&w2s[row * W2_LD + col]) =
            *reinterpret_cast<const ulonglong2*>(w2tb + row * 128 + col);
    }
    __syncthreads();

    int q = lane >> 4;       // 0..3: k-subblock / output row-group
    int m = lane & 15;       // column within tile
    int arow = wv * 16 + m;  // this lane's A row (node within tile)
    int hrow0 = wv * 16 + q * 4;

    // ---- GEMM1: H = A @ W1, 8 j-tiles, K=64 (2 MFMA each) ----
    bf16x8v a0 = *reinterpret_cast<const bf16x8v*>(&atile[arow * AT_LD + q * 8]);
    bf16x8v a1 = *reinterpret_cast<const bf16x8v*>(&atile[arow * AT_LD + 32 + q * 8]);
#pragma unroll
    for (int jt = 0; jt < 8; jt++) {
        int j = jt * 16 + m;
        bf16x8v bf0 = *reinterpret_cast<const bf16x8v*>(&w1s[j * W1_LD + q * 8]);
        bf16x8v bf1 = *reinterpret_cast<const bf16x8v*>(&w1s[j * W1_LD + 32 + q * 8]);
        f32x4 acc = {0.f, 0.f, 0.f, 0.f};
        acc = __builtin_amdgcn_mfma_f32_16x16x32_bf16(a0, bf0, acc, 0, 0, 0);
        acc = __builtin_amdgcn_mfma_f32_16x16x32_bf16(a1, bf1, acc, 0, 0, 0);
        float bv = b1v[j];
#pragma unroll
        for (int r = 0; r < 4; r++) {
            float hv = fmaxf(acc[r] + bv, 0.f);
            htile[(hrow0 + r) * HT_LD + j] = f2bf(hv);  // C/D: row=(l>>4)*4+r, col=l&15
        }
    }

    // ---- GEMM2: OUT = H @ W2, 4 d-tiles, K=128 (4 MFMA each) ----
    // wave-private rows: no __syncthreads needed (lgkmcnt orders ds ops)
    bf16x8v ha0 = *reinterpret_cast<const bf16x8v*>(&htile[arow * HT_LD + 0 * 32 + q * 8]);
    bf16x8v ha1 = *reinterpret_cast<const bf16x8v*>(&htile[arow * HT_LD + 1 * 32 + q * 8]);
    bf16x8v ha2 = *reinterpret_cast<const bf16x8v*>(&htile[arow * HT_LD + 2 * 32 + q * 8]);
    bf16x8v ha3 = *reinterpret_cast<const bf16x8v*>(&htile[arow * HT_LD + 3 * 32 + q * 8]);
#pragma unroll
    for (int dt = 0; dt < 4; dt++) {
        int d = dt * 16 + m;
        f32x4 acc = {0.f, 0.f, 0.f, 0.f};
        bf16x8v bw0 = *reinterpret_cast<const bf16x8v*>(&w2s[d * W2_LD + 0 * 32 + q * 8]);
        bf16x8v bw1 = *reinterpret_cast<const bf16x8v*>(&w2s[d * W2_LD + 1 * 32 + q * 8]);
        bf16x8v bw2 = *reinterpret_cast<const bf16x8v*>(&w2s[d * W2_LD + 2 * 32 + q * 8]);
        bf16x8v bw3 = *reinterpret_cast<const bf16x8v*>(&w2s[d * W2_LD + 3 * 32 + q * 8]);
        acc = __builtin_amdgcn_mfma_f32_16x16x32_bf16(ha0, bw0, acc, 0, 0, 0);
        acc = __builtin_amdgcn_mfma_f32_16x16x32_bf16(ha1, bw1, acc, 0, 0, 0);
        acc = __builtin_amdgcn_mfma_f32_16x16x32_bf16(ha2, bw2, acc, 0, 0, 0);
        acc = __builtin_amdgcn_mfma_f32_16x16x32_bf16(ha3, bw3, acc, 0, 0, 0);
        float bv = b2v[d];
#pragma unroll
        for (int r = 0; r < 4; r++) {
            int node = nb + hrow0 + r;
            if (node < N_NODES) out[(size_t)node * D_INF + d] = acc[r] + bv;
        }
    }
}

// ---------------------------------------------------------------------------
// Fallback (atomic scatter + convert) — used only if ws_size is too small
// ---------------------------------------------------------------------------

__global__ void init_agg_kernel(const float* __restrict__ x, float* __restrict__ agg) {
    int i = blockIdx.x * blockDim.x + threadIdx.x;
    int n4 = N_NODES * D_INF / 4;
    if (i < n4) {
        reinterpret_cast<float4*>(agg)[i] = reinterpret_cast<const float4*>(x)[i];
    }
}

__global__ void scatter_kernel(const float* __restrict__ x,
                               const int* __restrict__ src,
                               const int* __restrict__ dst,
                               float* __restrict__ agg) {
    int tid = blockIdx.x * blockDim.x + threadIdx.x;
    int e = tid >> 6;
    int d = tid & 63;
    if (e < N_EDGES) {
        atomicAdd(&agg[(size_t)dst[e] * D_INF + d], x[(size_t)src[e] * D_INF + d]);
    }
}

__global__ void cvt_agg_kernel(const float* __restrict__ agg32, ushort* __restrict__ aggb) {
    int i = blockIdx.x * blockDim.x + threadIdx.x;
    if (i < N_NODES * D_INF) aggb[i] = f2bf(agg32[i]);
}

// ---------------------------------------------------------------------------

extern "C" void kernel_launch(void* const* d_in, const int* in_sizes, int n_in,
                              void* d_out, int out_size, void* d_ws, size_t ws_size,
                              hipStream_t stream) {
    const float* x   = (const float*)d_in[0];
    const int* edge  = (const int*)d_in[1];   // [2, E]: src = edge, dst = edge + E
    const float* W1  = (const float*)d_in[2];
    const float* b1  = (const float*)d_in[3];
    const float* W2  = (const float*)d_in[4];
    const float* b2  = (const float*)d_in[5];
    float* out       = (float*)d_out;

    const int* src = edge;
    const int* dst = edge + N_EDGES;

    // Workspace layout:
    //   aggb  : N*64 bf16   (6.4 MB)
    //   w1tb  : 128*64 bf16 (16 KB)     w2tb: 64*128 bf16 (16 KB)
    //   cnt/cursor: N ints each;  rowptr: N+1;  bsum: 64;  elist: E ints
    //   agg32 (fallback only): N*64 floats, after elist, 16B-aligned
    ushort* aggb = (ushort*)d_ws;
    ushort* w1tb = aggb + (size_t)N_NODES * D_INF;
    ushort* w2tb = w1tb + D_INF * D_HIDF;
    int* cnt     = (int*)(w2tb + D_INF * D_HIDF);
    int* cursor  = cnt + N_NODES;
    int* rowptr  = cursor + N_NODES;
    int* bsum    = rowptr + N_NODES + 1;
    int* elist   = bsum + 64;
    float* agg32 = (float*)(((uintptr_t)(elist + N_EDGES) + 15) & ~(uintptr_t)15);

    size_t needed_csr = (uintptr_t)(elist + N_EDGES) - (uintptr_t)d_ws;

    prep_weights_kernel<<<(D_INF * D_HIDF + 255) / 256, 256, 0, stream>>>(W1, W2, w1tb, w2tb);

    if (ws_size >= needed_csr) {
        zero_kernel<<<(N_NODES + 255) / 256, 256, 0, stream>>>(cnt, N_NODES);
        hist_kernel<<<(N_EDGES + 255) / 256, 256, 0, stream>>>(dst, cnt);
        scan1_kernel<<<SCAN_NBLK, 256, 0, stream>>>(cnt, rowptr, bsum);
        scan2_kernel<<<1, 64, 0, stream>>>(bsum);
        scan3_kernel<<<SCAN_NBLK, 256, 0, stream>>>(rowptr, bsum, cursor);
        fill_kernel<<<(N_EDGES + 255) / 256, 256, 0, stream>>>(src, dst, cursor, elist);
        int threads = N_NODES * 64;
        gather_kernel<<<(threads + 255) / 256, 256, 0, stream>>>(x, rowptr, elist, aggb);
    } else {
        int n4 = N_NODES * D_INF / 4;
        init_agg_kernel<<<(n4 + 255) / 256, 256, 0, stream>>>(x, agg32);
        int work = N_EDGES * D_INF;
        scatter_kernel<<<(work + 255) / 256, 256, 0, stream>>>(x, src, dst, agg32);
        cvt_agg_kernel<<<(N_NODES * D_INF + 255) / 256, 256, 0, stream>>>(agg32, aggb);
    }

    // MLP: 64-node tiles, 4 waves/block, bf16 MFMA
    mlp_mfma_kernel<<<(N_NODES + 63) / 64, 256, 0, stream>>>(aggb, w1tb, b1, w2tb, b2, out);
}